// Round 8
// baseline (355.584 us; speedup 1.0000x reference)
//
#include <hip/hip_runtime.h>
#include <string.h>

#define NN 30000
#define NE 480000
#define CAP 96
#define KSC (0.0625f * 1.44269504f)   // SCALE * log2(e): exp(q*k/16) = exp2(q*kk)

typedef __attribute__((ext_vector_type(8))) _Float16 f16x8;
typedef __attribute__((ext_vector_type(4))) float f32x4;
typedef __attribute__((ext_vector_type(4))) int i32x4;

__device__ __forceinline__ unsigned short f2h(float f) {
    _Float16 h = (_Float16)f;
    unsigned short u;
    memcpy(&u, &h, 2);
    return u;
}

__device__ __forceinline__ void gload16(const void* g, void* l) {
    __builtin_amdgcn_global_load_lds(
        (const __attribute__((address_space(1))) unsigned int*)g,
        (__attribute__((address_space(3))) unsigned int*)l, 16, 0, 0);
}

// ---------------- LayerNorm -> fp16 x ----------------
__global__ __launch_bounds__(256) void ln_kernel(const float* __restrict__ s,
                                                 const float* __restrict__ gamma,
                                                 const float* __restrict__ beta,
                                                 unsigned short* __restrict__ xh) {
    const int n = blockIdx.x;
    const int c = threadIdx.x;
    float v = s[n * 256 + c];
    float sum = v, sq = v * v;
    for (int o = 32; o; o >>= 1) {
        sum += __shfl_down(sum, o, 64);
        sq  += __shfl_down(sq,  o, 64);
    }
    __shared__ float ssum[4], ssq[4];
    const int wave = c >> 6, lane = c & 63;
    if (lane == 0) { ssum[wave] = sum; ssq[wave] = sq; }
    __syncthreads();
    float ts = ssum[0] + ssum[1] + ssum[2] + ssum[3];
    float tq = ssq[0]  + ssq[1]  + ssq[2]  + ssq[3];
    float mu  = ts * (1.0f / 256.0f);
    float var = tq * (1.0f / 256.0f) - mu * mu;
    float x = (v - mu) * rsqrtf(var + 1e-5f) * gamma[c] + beta[c];
    xh[n * 256 + c] = f2h(x);
}

// ---------------- Wqkv [256,768] f32 -> WT [768,256] fp16 ----------------
__global__ __launch_bounds__(256) void wt_kernel(const float* __restrict__ W,
                                                 unsigned short* __restrict__ WT) {
    const int idx = blockIdx.x * 256 + threadIdx.x;
    if (idx < 768 * 256) {
        const int n = idx >> 8;
        const int k = idx & 255;
        WT[idx] = f2h(W[k * 768 + n]);
    }
}

// ---------------- init: zero cursor+hist, sentinel-fill col, zero sentinel rows ----
__global__ __launch_bounds__(256) void init_kernel(int* __restrict__ cur,
                                                   int* __restrict__ hist,
                                                   unsigned int* __restrict__ colu,   // NN*CAP/2 uints
                                                   unsigned int* __restrict__ qs,
                                                   unsigned int* __restrict__ vs) {
    const int i = blockIdx.x * 256 + threadIdx.x;
    const unsigned int sent2 = (unsigned int)NN | ((unsigned int)NN << 16);
    if (i < NN * CAP / 2) colu[i] = sent2;
    if (i < NN) cur[i] = 0;
    if (i < CAP + 1) hist[i] = 0;
    if (i < 8 * 16) {  // 8 slices x 16 uints = sentinel row (32 ushorts) of qs/vs
        const int x = i >> 4, j = i & 15;
        qs[((size_t)x * (NN + 1) + NN) * 16 + j] = 0u;
        vs[((size_t)x * (NN + 1) + NN) * 16 + j] = 0u;
    }
}

__global__ __launch_bounds__(256) void scatter_kernel(const int* __restrict__ src,
                                                      const int* __restrict__ dst,
                                                      int* __restrict__ cursor,
                                                      unsigned short* __restrict__ col) {
    const int e = blockIdx.x * 256 + threadIdx.x;
    if (e < NE) {
        const int d = dst[e];
        const int slot = atomicAdd(&cursor[d], 1);
        if (slot < CAP) col[d * CAP + slot] = (unsigned short)src[e];
    }
}

// ---------------- degree counting-sort ----------------
__global__ __launch_bounds__(256) void hist_kernel(const int* __restrict__ cur,
                                                   int* __restrict__ hist) {
    const int i = blockIdx.x * 256 + threadIdx.x;
    if (i < NN) {
        int d = cur[i];
        if (d > CAP) d = CAP;
        atomicAdd(&hist[d], 1);
    }
}

__global__ void scan_kernel(const int* __restrict__ hist, int* __restrict__ offs) {
    if (threadIdx.x == 0) {
        int run = 0;
        for (int d = 0; d <= CAP; ++d) { offs[d] = run; run += hist[d]; }
    }
}

__global__ __launch_bounds__(256) void rank_kernel(const int* __restrict__ cur,
                                                   int* __restrict__ offs,
                                                   int* __restrict__ perm) {
    const int i = blockIdx.x * 256 + threadIdx.x;
    if (i < NN) {
        int d = cur[i];
        if (d > CAP) d = CAP;
        const int r = atomicAdd(&offs[d], 1);
        perm[r] = i;
    }
}

// ---------------- GEMM: m97-style, XCD-banded, sliced epilogue ----------------
#define BM 128
#define BN 128
#define BK 32
#define CSTRIDE 136
#define MTILES 235   // ceil(30000/128)

__global__ __launch_bounds__(256) void gemm_kernel(const unsigned short* __restrict__ A,
                                                   const unsigned short* __restrict__ B,
                                                   unsigned short* __restrict__ qb,   // [8][NN+1][32]
                                                   unsigned short* __restrict__ kb,   // [8][NN][32]
                                                   unsigned short* __restrict__ vb) { // [8][NN+1][32]
    const int f   = blockIdx.x;          // 0..1439
    const int xcd = f & 7;
    const int i   = f >> 3;              // 0..179
    const int bmi = xcd * 30 + i / 6;
    if (bmi >= MTILES) return;
    const int bm = bmi * BM;
    const int by = i % 6;
    const int bn = by * BN;

    __shared__ unsigned short smem[BM * CSTRIDE];
    unsigned short* As = smem;
    unsigned short* Bs = smem + 4096;

    const int tid  = threadIdx.x;
    const int lane = tid & 63;
    const int wave = tid >> 6;
    const int wm = (wave & 1) * 64;
    const int wn = (wave >> 1) * 64;
    const int l16  = lane & 15;
    const int quad = lane >> 4;

    const int srow = wave * 16 + (lane >> 2);
    const int ko   = (lane & 3) * 8;

    int gmA0 = bm + srow;       if (gmA0 >= NN) gmA0 = NN - 1;
    int gmA1 = bm + srow + 64;  if (gmA1 >= NN) gmA1 = NN - 1;
    const int gnB0 = bn + srow;
    const int gnB1 = bn + srow + 64;

    f32x4 acc[4][4] = {};

    for (int kt = 0; kt < 256; kt += BK) {
        gload16(A + (size_t)gmA0 * 256 + kt + ko, &As[(wave * 16) * 32]);
        gload16(A + (size_t)gmA1 * 256 + kt + ko, &As[(64 + wave * 16) * 32]);
        gload16(B + (size_t)gnB0 * 256 + kt + ko, &Bs[(wave * 16) * 32]);
        gload16(B + (size_t)gnB1 * 256 + kt + ko, &Bs[(64 + wave * 16) * 32]);
        __syncthreads();

        f16x8 af[4], bfr[4];
        #pragma unroll
        for (int ii = 0; ii < 4; ii++)
            af[ii]  = *(const f16x8*)(&As[(wm + ii * 16 + l16) * 32 + quad * 8]);
        #pragma unroll
        for (int j = 0; j < 4; j++)
            bfr[j] = *(const f16x8*)(&Bs[(wn + j * 16 + l16) * 32 + quad * 8]);
        #pragma unroll
        for (int ii = 0; ii < 4; ii++)
            #pragma unroll
            for (int j = 0; j < 4; j++)
                acc[ii][j] = __builtin_amdgcn_mfma_f32_16x16x32_f16(af[ii], bfr[j], acc[ii][j], 0, 0, 0);
        __syncthreads();
    }

    #pragma unroll
    for (int ii = 0; ii < 4; ii++)
        #pragma unroll
        for (int j = 0; j < 4; j++)
            #pragma unroll
            for (int r = 0; r < 4; r++)
                smem[(wm + ii * 16 + quad * 4 + r) * CSTRIDE + wn + j * 16 + l16] =
                    f2h(acc[ii][j][r]);
    __syncthreads();

    const int sector  = by >> 1;                 // 0=q,1=k,2=v
    const int colhalf = (by & 1) * 128;
    const int row  = tid >> 1;
    const int cseg = (tid & 1) * 64;
    const int grow = bm + row;
    if (grow < NN) {
        #pragma unroll
        for (int k = 0; k < 8; k++) {
            i32x4 val = *(const i32x4*)(&smem[row * CSTRIDE + cseg + k * 8]);
            const int c = colhalf + cseg + k * 8;    // 8-aligned, 0..255
            const int x = c >> 5;                    // slice
            if (sector == 1)
                *(i32x4*)(kb + ((size_t)x * NN + grow) * 32 + (c & 31)) = val;
            else if (sector == 0)
                *(i32x4*)(qb + ((size_t)x * (NN + 1) + grow) * 32 + (c & 31)) = val;
            else
                *(i32x4*)(vb + ((size_t)x * (NN + 1) + grow) * 32 + (c & 31)) = val;
        }
    }
}

// ---------------- edge: r6 shape + sentinel padding + degree-sorted nodes ----------------
__global__ __launch_bounds__(256) void edge_kernel(const unsigned short* __restrict__ qs,  // [8][NN+1][32]
                                                   const unsigned short* __restrict__ vs,  // [8][NN+1][32]
                                                   const unsigned short* __restrict__ ks,  // [8][NN][32]
                                                   const int* __restrict__ cursor,
                                                   const unsigned short* __restrict__ col, // [NN][CAP] sentinel-padded
                                                   const int* __restrict__ perm,
                                                   float* __restrict__ out) {
    const int x   = blockIdx.x;            // slice 0..7 -> XCD (round-robin)
    const int nb  = blockIdx.y * 16;
    const int tid = threadIdx.x;
    const int wave = tid >> 6;
    const int lane = tid & 63;

    __shared__ unsigned short scol[16 * CAP];   // 3072 B
    __shared__ int sdeg[16];
    __shared__ int snode[16];

    if (tid < 16) {
        const int m = perm[nb + tid];
        snode[tid] = m;
        int d = cursor[m];
        sdeg[tid] = (d > CAP) ? CAP : d;
    }
    __syncthreads();
    {
        const unsigned int* colu = (const unsigned int*)col;
        unsigned int* scolu = (unsigned int*)scol;
        #pragma unroll
        for (int j = 0; j < 3; j++) {
            const int t2 = tid + j * 256;            // 0..767
            const int nd = t2 / 48;                  // local node
            const int ps = t2 - nd * 48;
            scolu[t2] = colu[snode[nd] * 48 + ps];
        }
    }
    __syncthreads();

    const int g     = lane >> 4;            // node-in-wave 0..3
    const int cpair = lane & 15;            // channel pair
    const int li    = wave * 4 + g;
    const int m     = snode[li];            // true node id

    const int mydeg = sdeg[li];
    int dmax = sdeg[wave * 4];
    dmax = max(dmax, sdeg[wave * 4 + 1]);
    dmax = max(dmax, sdeg[wave * 4 + 2]);
    dmax = max(dmax, sdeg[wave * 4 + 3]);   // sorted -> dmax ~ mydeg

    union H2 { unsigned int u; _Float16 h[2]; };
    H2 kw;
    kw.u = *(const unsigned int*)(ks + ((size_t)x * NN + m) * 32 + 2 * cpair);
    const float kk0 = (float)kw.h[0] * KSC;
    const float kk1 = (float)kw.h[1] * KSC;

    const unsigned short* qp = qs + (size_t)x * (NN + 1) * 32 + 2 * cpair;
    const unsigned short* vp = vs + (size_t)x * (NN + 1) * 32 + 2 * cpair;
    const unsigned short* myscol = &scol[li * CAP];

    float z0 = 0.f, z1 = 0.f, a0 = 0.f, a1 = 0.f;

    int i = 0;
    for (; i + 4 <= dmax; i += 4) {
        #pragma unroll
        for (int j = 0; j < 4; j++) {
            const int s = myscol[i + j];             // sentinel NN when padded
            H2 qd, vd;
            qd.u = *(const unsigned int*)(qp + (size_t)s * 32);
            vd.u = *(const unsigned int*)(vp + (size_t)s * 32);
            const float w0 = __builtin_exp2f((float)qd.h[0] * kk0);
            const float w1 = __builtin_exp2f((float)qd.h[1] * kk1);
            z0 += w0; a0 += w0 * (float)vd.h[0];
            z1 += w1; a1 += w1 * (float)vd.h[1];
        }
    }
    for (; i < dmax; ++i) {
        const int s = myscol[i];
        H2 qd, vd;
        qd.u = *(const unsigned int*)(qp + (size_t)s * 32);
        vd.u = *(const unsigned int*)(vp + (size_t)s * 32);
        const float w0 = __builtin_exp2f((float)qd.h[0] * kk0);
        const float w1 = __builtin_exp2f((float)qd.h[1] * kk1);
        z0 += w0; a0 += w0 * (float)vd.h[0];
        z1 += w1; a1 += w1 * (float)vd.h[1];
    }

    // sentinel pads contributed exactly 1.0 to z, 0.0 to a — exact correction:
    const float npad = (float)(dmax - mydeg);
    z0 -= npad;
    z1 -= npad;

    float2 o;
    o.x = (mydeg > 0) ? a0 / z0 : 0.0f;
    o.y = (mydeg > 0) ? a1 / z1 : 0.0f;
    *(float2*)(out + (size_t)m * 256 + x * 32 + 2 * cpair) = o;
}

extern "C" void kernel_launch(void* const* d_in, const int* in_sizes, int n_in,
                              void* d_out, int out_size, void* d_ws, size_t ws_size,
                              hipStream_t stream) {
    const float* s     = (const float*)d_in[0];
    const float* Wqkv  = (const float*)d_in[1];
    const float* gamma = (const float*)d_in[2];
    const float* beta  = (const float*)d_in[3];
    const int*   src   = (const int*)d_in[4];
    const int*   dst   = (const int*)d_in[5];
    float* out = (float*)d_out;

    char* ws = (char*)d_ws;
    unsigned short* xh   = (unsigned short*)(ws);                   // 15,360,000
    unsigned short* WT   = (unsigned short*)(ws + 15360000);        //    393,216
    unsigned short* qs   = (unsigned short*)(ws + 15753216);        // 15,360,512  [8][NN+1][32]
    unsigned short* vs   = (unsigned short*)(ws + 31113728);        // 15,360,512
    unsigned short* ks   = (unsigned short*)(ws + 46474240);        // 15,360,000  [8][NN][32]
    int*            cur  = (int*)(ws + 61834240);                   //    120,000
    unsigned short* col  = (unsigned short*)(ws + 61954240);        //  5,760,000
    int*            hist = (int*)(ws + 67714240);                   //        512
    int*            offs = (int*)(ws + 67714752);                   //        512
    int*            perm = (int*)(ws + 67715264);                   //    120,000  (~67.8 MB)

    ln_kernel<<<NN, 256, 0, stream>>>(s, gamma, beta, xh);
    wt_kernel<<<(768 * 256 + 255) / 256, 256, 0, stream>>>(Wqkv, WT);
    init_kernel<<<(NN * CAP / 2 + 255) / 256, 256, 0, stream>>>(
        cur, hist, (unsigned int*)col, (unsigned int*)qs, (unsigned int*)vs);
    scatter_kernel<<<(NE + 255) / 256, 256, 0, stream>>>(src, dst, cur, col);
    hist_kernel<<<(NN + 255) / 256, 256, 0, stream>>>(cur, hist);
    scan_kernel<<<1, 64, 0, stream>>>(hist, offs);
    rank_kernel<<<(NN + 255) / 256, 256, 0, stream>>>(cur, offs, perm);
    gemm_kernel<<<1440, 256, 0, stream>>>(xh, WT, qs, ks, vs);
    edge_kernel<<<dim3(8, NN / 16), 256, 0, stream>>>(qs, vs, ks, cur, col, perm, out);
}

// Round 9
// 234.426 us; speedup vs baseline: 1.5168x; 1.5168x over previous
//
#include <hip/hip_runtime.h>
#include <string.h>

#define NN 30000
#define NE 480000
#define CAP 96
#define KSC (0.0625f * 1.44269504f)   // SCALE * log2(e): exp(q*k/16) = exp2(q*kk)

typedef __attribute__((ext_vector_type(8))) _Float16 f16x8;
typedef __attribute__((ext_vector_type(4))) float f32x4;
typedef __attribute__((ext_vector_type(4))) int i32x4;

__device__ __forceinline__ unsigned short f2h(float f) {
    _Float16 h = (_Float16)f;
    unsigned short u;
    memcpy(&u, &h, 2);
    return u;
}

__device__ __forceinline__ void gload16(const void* g, void* l) {
    __builtin_amdgcn_global_load_lds(
        (const __attribute__((address_space(1))) unsigned int*)g,
        (__attribute__((address_space(3))) unsigned int*)l, 16, 0, 0);
}

// ---------------- LayerNorm -> fp16 x ----------------
__global__ __launch_bounds__(256) void ln_kernel(const float* __restrict__ s,
                                                 const float* __restrict__ gamma,
                                                 const float* __restrict__ beta,
                                                 unsigned short* __restrict__ xh) {
    const int n = blockIdx.x;
    const int c = threadIdx.x;
    float v = s[n * 256 + c];
    float sum = v, sq = v * v;
    for (int o = 32; o; o >>= 1) {
        sum += __shfl_down(sum, o, 64);
        sq  += __shfl_down(sq,  o, 64);
    }
    __shared__ float ssum[4], ssq[4];
    const int wave = c >> 6, lane = c & 63;
    if (lane == 0) { ssum[wave] = sum; ssq[wave] = sq; }
    __syncthreads();
    float ts = ssum[0] + ssum[1] + ssum[2] + ssum[3];
    float tq = ssq[0]  + ssq[1]  + ssq[2]  + ssq[3];
    float mu  = ts * (1.0f / 256.0f);
    float var = tq * (1.0f / 256.0f) - mu * mu;
    float x = (v - mu) * rsqrtf(var + 1e-5f) * gamma[c] + beta[c];
    xh[n * 256 + c] = f2h(x);
}

// ---------------- Wqkv [256,768] f32 -> WT [768,256] fp16 ----------------
__global__ __launch_bounds__(256) void wt_kernel(const float* __restrict__ W,
                                                 unsigned short* __restrict__ WT) {
    const int idx = blockIdx.x * 256 + threadIdx.x;
    if (idx < 768 * 256) {
        const int n = idx >> 8;
        const int k = idx & 255;
        WT[idx] = f2h(W[k * 768 + n]);
    }
}

// ---------------- init: zero cursor, sentinel-fill col, zero sentinel rows ----
__global__ __launch_bounds__(256) void init_kernel(int* __restrict__ cur,
                                                   unsigned int* __restrict__ colu,   // NN*CAP/2 uints
                                                   unsigned int* __restrict__ qs,
                                                   unsigned int* __restrict__ vs) {
    const int i = blockIdx.x * 256 + threadIdx.x;
    const unsigned int sent2 = (unsigned int)NN | ((unsigned int)NN << 16);
    if (i < NN * CAP / 2) colu[i] = sent2;
    if (i < NN) cur[i] = 0;
    if (i < 8 * 16) {  // 8 slices x 16 uints = sentinel row (32 ushorts) of qs/vs
        const int x = i >> 4, j = i & 15;
        qs[((size_t)x * (NN + 1) + NN) * 16 + j] = 0u;
        vs[((size_t)x * (NN + 1) + NN) * 16 + j] = 0u;
    }
}

__global__ __launch_bounds__(256) void scatter_kernel(const int* __restrict__ src,
                                                      const int* __restrict__ dst,
                                                      int* __restrict__ cursor,
                                                      unsigned short* __restrict__ col) {
    const int e = blockIdx.x * 256 + threadIdx.x;
    if (e < NE) {
        const int d = dst[e];
        const int slot = atomicAdd(&cursor[d], 1);
        if (slot < CAP) col[d * CAP + slot] = (unsigned short)src[e];
    }
}

// ---------------- GEMM: m97-style, XCD-banded, sliced epilogue ----------------
#define BM 128
#define BN 128
#define BK 32
#define CSTRIDE 136
#define MTILES 235   // ceil(30000/128)

__global__ __launch_bounds__(256) void gemm_kernel(const unsigned short* __restrict__ A,
                                                   const unsigned short* __restrict__ B,
                                                   unsigned short* __restrict__ qb,   // [8][NN+1][32]
                                                   unsigned short* __restrict__ kb,   // [8][NN][32]
                                                   unsigned short* __restrict__ vb) { // [8][NN+1][32]
    const int f   = blockIdx.x;          // 0..1439
    const int xcd = f & 7;
    const int i   = f >> 3;              // 0..179
    const int bmi = xcd * 30 + i / 6;
    if (bmi >= MTILES) return;
    const int bm = bmi * BM;
    const int by = i % 6;
    const int bn = by * BN;

    __shared__ unsigned short smem[BM * CSTRIDE];
    unsigned short* As = smem;
    unsigned short* Bs = smem + 4096;

    const int tid  = threadIdx.x;
    const int lane = tid & 63;
    const int wave = tid >> 6;
    const int wm = (wave & 1) * 64;
    const int wn = (wave >> 1) * 64;
    const int l16  = lane & 15;
    const int quad = lane >> 4;

    const int srow = wave * 16 + (lane >> 2);
    const int ko   = (lane & 3) * 8;

    int gmA0 = bm + srow;       if (gmA0 >= NN) gmA0 = NN - 1;
    int gmA1 = bm + srow + 64;  if (gmA1 >= NN) gmA1 = NN - 1;
    const int gnB0 = bn + srow;
    const int gnB1 = bn + srow + 64;

    f32x4 acc[4][4] = {};

    for (int kt = 0; kt < 256; kt += BK) {
        gload16(A + (size_t)gmA0 * 256 + kt + ko, &As[(wave * 16) * 32]);
        gload16(A + (size_t)gmA1 * 256 + kt + ko, &As[(64 + wave * 16) * 32]);
        gload16(B + (size_t)gnB0 * 256 + kt + ko, &Bs[(wave * 16) * 32]);
        gload16(B + (size_t)gnB1 * 256 + kt + ko, &Bs[(64 + wave * 16) * 32]);
        __syncthreads();

        f16x8 af[4], bfr[4];
        #pragma unroll
        for (int ii = 0; ii < 4; ii++)
            af[ii]  = *(const f16x8*)(&As[(wm + ii * 16 + l16) * 32 + quad * 8]);
        #pragma unroll
        for (int j = 0; j < 4; j++)
            bfr[j] = *(const f16x8*)(&Bs[(wn + j * 16 + l16) * 32 + quad * 8]);
        #pragma unroll
        for (int ii = 0; ii < 4; ii++)
            #pragma unroll
            for (int j = 0; j < 4; j++)
                acc[ii][j] = __builtin_amdgcn_mfma_f32_16x16x32_f16(af[ii], bfr[j], acc[ii][j], 0, 0, 0);
        __syncthreads();
    }

    #pragma unroll
    for (int ii = 0; ii < 4; ii++)
        #pragma unroll
        for (int j = 0; j < 4; j++)
            #pragma unroll
            for (int r = 0; r < 4; r++)
                smem[(wm + ii * 16 + quad * 4 + r) * CSTRIDE + wn + j * 16 + l16] =
                    f2h(acc[ii][j][r]);
    __syncthreads();

    const int sector  = by >> 1;                 // 0=q,1=k,2=v
    const int colhalf = (by & 1) * 128;
    const int row  = tid >> 1;
    const int cseg = (tid & 1) * 64;
    const int grow = bm + row;
    if (grow < NN) {
        #pragma unroll
        for (int k = 0; k < 8; k++) {
            i32x4 val = *(const i32x4*)(&smem[row * CSTRIDE + cseg + k * 8]);
            const int c = colhalf + cseg + k * 8;    // 8-aligned, 0..255
            const int x = c >> 5;                    // slice
            if (sector == 1)
                *(i32x4*)(kb + ((size_t)x * NN + grow) * 32 + (c & 31)) = val;
            else if (sector == 0)
                *(i32x4*)(qb + ((size_t)x * (NN + 1) + grow) * 32 + (c & 31)) = val;
            else
                *(i32x4*)(vb + ((size_t)x * (NN + 1) + grow) * 32 + (c & 31)) = val;
        }
    }
}

// ---------------- edge: r6 shape + sentinel padding (no sort) ----------------
__global__ __launch_bounds__(256) void edge_kernel(const unsigned short* __restrict__ qs,  // [8][NN+1][32]
                                                   const unsigned short* __restrict__ vs,  // [8][NN+1][32]
                                                   const unsigned short* __restrict__ ks,  // [8][NN][32]
                                                   const int* __restrict__ cursor,
                                                   const unsigned short* __restrict__ col, // [NN][CAP] sentinel-padded
                                                   float* __restrict__ out) {
    const int x    = blockIdx.x;            // slice 0..7 -> XCD (round-robin)
    const int nb   = blockIdx.y * 16;       // block's 16 nodes (sequential)
    const int tid  = threadIdx.x;
    const int wave = tid >> 6;
    const int lane = tid & 63;

    __shared__ unsigned short scol[16 * CAP];   // 3072 B
    __shared__ int sdeg[16];

    if (tid < 16) {
        int d = cursor[nb + tid];
        sdeg[tid] = (d > CAP) ? CAP : d;
    }
    {
        const unsigned int* colu = (const unsigned int*)(col + (size_t)nb * CAP);
        unsigned int* scolu = (unsigned int*)scol;
        #pragma unroll
        for (int j = 0; j < 3; j++) scolu[tid + j * 256] = colu[tid + j * 256];
    }
    __syncthreads();

    const int g     = lane >> 4;            // node-in-wave 0..3
    const int cpair = lane & 15;            // channel pair
    const int li    = wave * 4 + g;
    const int n     = nb + li;

    const int mydeg = sdeg[li];
    int dmax = sdeg[wave * 4];
    dmax = max(dmax, sdeg[wave * 4 + 1]);
    dmax = max(dmax, sdeg[wave * 4 + 2]);
    dmax = max(dmax, sdeg[wave * 4 + 3]);

    union H2 { unsigned int u; _Float16 h[2]; };
    H2 kw;
    kw.u = *(const unsigned int*)(ks + ((size_t)x * NN + n) * 32 + 2 * cpair);
    const float kk0 = (float)kw.h[0] * KSC;
    const float kk1 = (float)kw.h[1] * KSC;

    const unsigned short* qp = qs + (size_t)x * (NN + 1) * 32 + 2 * cpair;
    const unsigned short* vp = vs + (size_t)x * (NN + 1) * 32 + 2 * cpair;
    const unsigned short* myscol = &scol[li * CAP];

    float z0 = 0.f, z1 = 0.f, a0 = 0.f, a1 = 0.f;

    int i = 0;
    for (; i + 4 <= dmax; i += 4) {
        #pragma unroll
        for (int j = 0; j < 4; j++) {
            const int s = myscol[i + j];             // sentinel NN when padded
            H2 qd, vd;
            qd.u = *(const unsigned int*)(qp + (size_t)s * 32);
            vd.u = *(const unsigned int*)(vp + (size_t)s * 32);
            const float w0 = __builtin_exp2f((float)qd.h[0] * kk0);
            const float w1 = __builtin_exp2f((float)qd.h[1] * kk1);
            z0 += w0; a0 += w0 * (float)vd.h[0];
            z1 += w1; a1 += w1 * (float)vd.h[1];
        }
    }
    for (; i < dmax; ++i) {
        const int s = myscol[i];
        H2 qd, vd;
        qd.u = *(const unsigned int*)(qp + (size_t)s * 32);
        vd.u = *(const unsigned int*)(vp + (size_t)s * 32);
        const float w0 = __builtin_exp2f((float)qd.h[0] * kk0);
        const float w1 = __builtin_exp2f((float)qd.h[1] * kk1);
        z0 += w0; a0 += w0 * (float)vd.h[0];
        z1 += w1; a1 += w1 * (float)vd.h[1];
    }

    // sentinel pads contributed exactly 1.0 to z, 0.0 to a — exact correction:
    const float npad = (float)(dmax - mydeg);
    z0 -= npad;
    z1 -= npad;

    float2 o;
    o.x = (mydeg > 0) ? a0 / z0 : 0.0f;
    o.y = (mydeg > 0) ? a1 / z1 : 0.0f;
    *(float2*)(out + (size_t)n * 256 + x * 32 + 2 * cpair) = o;
}

extern "C" void kernel_launch(void* const* d_in, const int* in_sizes, int n_in,
                              void* d_out, int out_size, void* d_ws, size_t ws_size,
                              hipStream_t stream) {
    const float* s     = (const float*)d_in[0];
    const float* Wqkv  = (const float*)d_in[1];
    const float* gamma = (const float*)d_in[2];
    const float* beta  = (const float*)d_in[3];
    const int*   src   = (const int*)d_in[4];
    const int*   dst   = (const int*)d_in[5];
    float* out = (float*)d_out;

    char* ws = (char*)d_ws;
    unsigned short* xh   = (unsigned short*)(ws);                   // 15,360,000
    unsigned short* WT   = (unsigned short*)(ws + 15360000);        //    393,216
    unsigned short* qs   = (unsigned short*)(ws + 15753216);        // 15,360,512  [8][NN+1][32]
    unsigned short* vs   = (unsigned short*)(ws + 31113728);        // 15,360,512
    unsigned short* ks   = (unsigned short*)(ws + 46474240);        // 15,360,000  [8][NN][32]
    int*            cur  = (int*)(ws + 61834240);                   //    120,000
    unsigned short* col  = (unsigned short*)(ws + 61954240);        //  5,760,000  (~67.7 MB)

    ln_kernel<<<NN, 256, 0, stream>>>(s, gamma, beta, xh);
    wt_kernel<<<(768 * 256 + 255) / 256, 256, 0, stream>>>(Wqkv, WT);
    init_kernel<<<(NN * CAP / 2 + 255) / 256, 256, 0, stream>>>(
        cur, (unsigned int*)col, (unsigned int*)qs, (unsigned int*)vs);
    scatter_kernel<<<(NE + 255) / 256, 256, 0, stream>>>(src, dst, cur, col);
    gemm_kernel<<<1440, 256, 0, stream>>>(xh, WT, qs, ks, vs);
    edge_kernel<<<dim3(8, NN / 16), 256, 0, stream>>>(qs, vs, ks, cur, col, out);
}

// Round 10
// 216.245 us; speedup vs baseline: 1.6444x; 1.0841x over previous
//
#include <hip/hip_runtime.h>
#include <hip/hip_fp16.h>
#include <string.h>

#define NN 30000
#define NE 480000
#define CAP 96
#define KSC (0.0625f * 1.44269504f)   // SCALE * log2(e): exp(q*k/16) = exp2(q*kk)

typedef __attribute__((ext_vector_type(8))) _Float16 f16x8;
typedef __attribute__((ext_vector_type(4))) float f32x4;
typedef __attribute__((ext_vector_type(4))) int i32x4;

__device__ __forceinline__ unsigned short f2h(float f) {
    _Float16 h = (_Float16)f;
    unsigned short u;
    memcpy(&u, &h, 2);
    return u;
}

__device__ __forceinline__ void gload16(const void* g, void* l) {
    __builtin_amdgcn_global_load_lds(
        (const __attribute__((address_space(1))) unsigned int*)g,
        (__attribute__((address_space(3))) unsigned int*)l, 16, 0, 0);
}

// ---------------- LayerNorm -> fp16 x ----------------
__global__ __launch_bounds__(256) void ln_kernel(const float* __restrict__ s,
                                                 const float* __restrict__ gamma,
                                                 const float* __restrict__ beta,
                                                 unsigned short* __restrict__ xh) {
    const int n = blockIdx.x;
    const int c = threadIdx.x;
    float v = s[n * 256 + c];
    float sum = v, sq = v * v;
    for (int o = 32; o; o >>= 1) {
        sum += __shfl_down(sum, o, 64);
        sq  += __shfl_down(sq,  o, 64);
    }
    __shared__ float ssum[4], ssq[4];
    const int wave = c >> 6, lane = c & 63;
    if (lane == 0) { ssum[wave] = sum; ssq[wave] = sq; }
    __syncthreads();
    float ts = ssum[0] + ssum[1] + ssum[2] + ssum[3];
    float tq = ssq[0]  + ssq[1]  + ssq[2]  + ssq[3];
    float mu  = ts * (1.0f / 256.0f);
    float var = tq * (1.0f / 256.0f) - mu * mu;
    float x = (v - mu) * rsqrtf(var + 1e-5f) * gamma[c] + beta[c];
    xh[n * 256 + c] = f2h(x);
}

// ---------------- Wqkv [256,768] f32 -> WT [768,256] fp16 ----------------
__global__ __launch_bounds__(256) void wt_kernel(const float* __restrict__ W,
                                                 unsigned short* __restrict__ WT) {
    const int idx = blockIdx.x * 256 + threadIdx.x;
    if (idx < 768 * 256) {
        const int n = idx >> 8;
        const int k = idx & 255;
        WT[idx] = f2h(W[k * 768 + n]);
    }
}

// ---------------- init: zero cursor, sentinel-fill col, zero sentinel rows ----
__global__ __launch_bounds__(256) void init_kernel(int* __restrict__ cur,
                                                   unsigned int* __restrict__ colu,   // NN*CAP/2 uints
                                                   unsigned int* __restrict__ qs,
                                                   unsigned int* __restrict__ vs) {
    const int i = blockIdx.x * 256 + threadIdx.x;
    const unsigned int sent2 = (unsigned int)NN | ((unsigned int)NN << 16);
    if (i < NN * CAP / 2) colu[i] = sent2;
    if (i < NN) cur[i] = 0;
    if (i < 8 * 16) {  // 8 slices x 16 uints = sentinel row (32 ushorts) of qs/vs
        const int x = i >> 4, j = i & 15;
        qs[((size_t)x * (NN + 1) + NN) * 16 + j] = 0u;
        vs[((size_t)x * (NN + 1) + NN) * 16 + j] = 0u;
    }
}

__global__ __launch_bounds__(256) void scatter_kernel(const int* __restrict__ src,
                                                      const int* __restrict__ dst,
                                                      int* __restrict__ cursor,
                                                      unsigned short* __restrict__ col) {
    const int e = blockIdx.x * 256 + threadIdx.x;
    if (e < NE) {
        const int d = dst[e];
        const int slot = atomicAdd(&cursor[d], 1);
        if (slot < CAP) col[d * CAP + slot] = (unsigned short)src[e];
    }
}

// ---------------- GEMM: m97-style, XCD-banded, sliced epilogue ----------------
#define BM 128
#define BN 128
#define BK 32
#define CSTRIDE 136
#define MTILES 235   // ceil(30000/128)

__global__ __launch_bounds__(256) void gemm_kernel(const unsigned short* __restrict__ A,
                                                   const unsigned short* __restrict__ B,
                                                   unsigned short* __restrict__ qb,   // [8][NN+1][32]
                                                   unsigned short* __restrict__ kb,   // [8][NN][32]
                                                   unsigned short* __restrict__ vb) { // [8][NN+1][32]
    const int f   = blockIdx.x;          // 0..1439
    const int xcd = f & 7;
    const int i   = f >> 3;              // 0..179
    const int bmi = xcd * 30 + i / 6;
    if (bmi >= MTILES) return;
    const int bm = bmi * BM;
    const int by = i % 6;
    const int bn = by * BN;

    __shared__ unsigned short smem[BM * CSTRIDE];
    unsigned short* As = smem;
    unsigned short* Bs = smem + 4096;

    const int tid  = threadIdx.x;
    const int lane = tid & 63;
    const int wave = tid >> 6;
    const int wm = (wave & 1) * 64;
    const int wn = (wave >> 1) * 64;
    const int l16  = lane & 15;
    const int quad = lane >> 4;

    const int srow = wave * 16 + (lane >> 2);
    const int ko   = (lane & 3) * 8;

    int gmA0 = bm + srow;       if (gmA0 >= NN) gmA0 = NN - 1;
    int gmA1 = bm + srow + 64;  if (gmA1 >= NN) gmA1 = NN - 1;
    const int gnB0 = bn + srow;
    const int gnB1 = bn + srow + 64;

    f32x4 acc[4][4] = {};

    for (int kt = 0; kt < 256; kt += BK) {
        gload16(A + (size_t)gmA0 * 256 + kt + ko, &As[(wave * 16) * 32]);
        gload16(A + (size_t)gmA1 * 256 + kt + ko, &As[(64 + wave * 16) * 32]);
        gload16(B + (size_t)gnB0 * 256 + kt + ko, &Bs[(wave * 16) * 32]);
        gload16(B + (size_t)gnB1 * 256 + kt + ko, &Bs[(64 + wave * 16) * 32]);
        __syncthreads();

        f16x8 af[4], bfr[4];
        #pragma unroll
        for (int ii = 0; ii < 4; ii++)
            af[ii]  = *(const f16x8*)(&As[(wm + ii * 16 + l16) * 32 + quad * 8]);
        #pragma unroll
        for (int j = 0; j < 4; j++)
            bfr[j] = *(const f16x8*)(&Bs[(wn + j * 16 + l16) * 32 + quad * 8]);
        #pragma unroll
        for (int ii = 0; ii < 4; ii++)
            #pragma unroll
            for (int j = 0; j < 4; j++)
                acc[ii][j] = __builtin_amdgcn_mfma_f32_16x16x32_f16(af[ii], bfr[j], acc[ii][j], 0, 0, 0);
        __syncthreads();
    }

    #pragma unroll
    for (int ii = 0; ii < 4; ii++)
        #pragma unroll
        for (int j = 0; j < 4; j++)
            #pragma unroll
            for (int r = 0; r < 4; r++)
                smem[(wm + ii * 16 + quad * 4 + r) * CSTRIDE + wn + j * 16 + l16] =
                    f2h(acc[ii][j][r]);
    __syncthreads();

    const int sector  = by >> 1;                 // 0=q,1=k,2=v
    const int colhalf = (by & 1) * 128;
    const int row  = tid >> 1;
    const int cseg = (tid & 1) * 64;
    const int grow = bm + row;
    if (grow < NN) {
        #pragma unroll
        for (int k = 0; k < 8; k++) {
            i32x4 val = *(const i32x4*)(&smem[row * CSTRIDE + cseg + k * 8]);
            const int c = colhalf + cseg + k * 8;    // 8-aligned, 0..255
            const int x = c >> 5;                    // slice
            if (sector == 1)
                *(i32x4*)(kb + ((size_t)x * NN + grow) * 32 + (c & 31)) = val;
            else if (sector == 0)
                *(i32x4*)(qb + ((size_t)x * (NN + 1) + grow) * 32 + (c & 31)) = val;
            else
                *(i32x4*)(vb + ((size_t)x * (NN + 1) + grow) * 32 + (c & 31)) = val;
        }
    }
}

// ---------------- edge: in-block degree sort + sentinel + packed half2 ----------------
__global__ __launch_bounds__(256) void edge_kernel(const unsigned short* __restrict__ qs,  // [8][NN+1][32]
                                                   const unsigned short* __restrict__ vs,  // [8][NN+1][32]
                                                   const unsigned short* __restrict__ ks,  // [8][NN][32]
                                                   const int* __restrict__ cursor,
                                                   const unsigned short* __restrict__ col, // [NN][CAP] sentinel-padded
                                                   float* __restrict__ out) {
    const int x    = blockIdx.x;            // slice 0..7 -> XCD (round-robin)
    const int nb   = blockIdx.y * 16;       // block's 16 nodes (sequential band)
    const int tid  = threadIdx.x;
    const int wave = tid >> 6;
    const int lane = tid & 63;

    __shared__ unsigned short scol[16 * CAP];   // 3072 B
    __shared__ int sdegR[16];                   // raw degrees
    __shared__ int sdegS[16];                   // rank-sorted ascending
    __shared__ int snode[16];                   // node id at each rank

    if (tid < 16) {
        int d = cursor[nb + tid];
        sdegR[tid] = (d > CAP) ? CAP : d;
    }
    __syncthreads();
    if (tid < 16) {
        const int d = sdegR[tid];
        int r = 0;
        #pragma unroll
        for (int j = 0; j < 16; ++j) {
            const int dj = sdegR[j];
            r += (dj < d) || (dj == d && j < tid);
        }
        sdegS[r] = d;
        snode[r] = nb + tid;
    }
    __syncthreads();
    {   // stage col rows in sorted order
        const unsigned int* colu = (const unsigned int*)col;
        unsigned int* scolu = (unsigned int*)scol;
        #pragma unroll
        for (int j = 0; j < 3; j++) {
            const int t2 = tid + j * 256;            // 0..767
            const int nd = t2 / 48;                  // local rank
            const int ps = t2 - nd * 48;
            scolu[t2] = colu[snode[nd] * 48 + ps];
        }
    }
    __syncthreads();

    const int g     = lane >> 4;            // node-in-wave 0..3
    const int cpair = lane & 15;            // channel pair
    const int li    = wave * 4 + g;
    const int m     = snode[li];            // true node id

    const int mydeg = sdegS[li];
    const int dmax4 = (sdegS[wave * 4 + 3] + 3) & ~3;   // sorted: quartet max is rank 3

    union H2 { unsigned int u; __half2 h; };
    H2 kw;
    kw.u = *(const unsigned int*)(ks + ((size_t)x * NN + m) * 32 + 2 * cpair);
    const __half2 kk2 = __hmul2(kw.h, __float2half2_rn(KSC));

    const unsigned short* qp = qs + (size_t)x * (NN + 1) * 32 + 2 * cpair;
    const unsigned short* vp = vs + (size_t)x * (NN + 1) * 32 + 2 * cpair;
    const unsigned short* myscol = &scol[li * CAP];

    __half2 z2 = __float2half2_rn(0.0f);
    __half2 a2 = __float2half2_rn(0.0f);

    for (int i = 0; i < dmax4; i += 4) {
        #pragma unroll
        for (int j = 0; j < 4; j++) {
            const int s = myscol[i + j];             // sentinel NN when padded
            H2 qd, vd;
            qd.u = *(const unsigned int*)(qp + (size_t)s * 32);
            vd.u = *(const unsigned int*)(vp + (size_t)s * 32);
            const __half2 w = h2exp2(__hmul2(qd.h, kk2));   // sentinel: exp2(0)=1 exact
            z2 = __hadd2(z2, w);
            a2 = __hfma2(w, vd.h, a2);
        }
    }

    // sentinel pads contributed exactly 1.0 to z, 0.0 to a — exact correction:
    const float npad = (float)(dmax4 - mydeg);
    const float z0 = __low2float(z2)  - npad;
    const float z1 = __high2float(z2) - npad;
    const float a0 = __low2float(a2);
    const float a1 = __high2float(a2);

    float2 o;
    o.x = (mydeg > 0) ? a0 / z0 : 0.0f;
    o.y = (mydeg > 0) ? a1 / z1 : 0.0f;
    *(float2*)(out + (size_t)m * 256 + x * 32 + 2 * cpair) = o;
}

extern "C" void kernel_launch(void* const* d_in, const int* in_sizes, int n_in,
                              void* d_out, int out_size, void* d_ws, size_t ws_size,
                              hipStream_t stream) {
    const float* s     = (const float*)d_in[0];
    const float* Wqkv  = (const float*)d_in[1];
    const float* gamma = (const float*)d_in[2];
    const float* beta  = (const float*)d_in[3];
    const int*   src   = (const int*)d_in[4];
    const int*   dst   = (const int*)d_in[5];
    float* out = (float*)d_out;

    char* ws = (char*)d_ws;
    unsigned short* xh   = (unsigned short*)(ws);                   // 15,360,000
    unsigned short* WT   = (unsigned short*)(ws + 15360000);        //    393,216
    unsigned short* qs   = (unsigned short*)(ws + 15753216);        // 15,360,512  [8][NN+1][32]
    unsigned short* vs   = (unsigned short*)(ws + 31113728);        // 15,360,512
    unsigned short* ks   = (unsigned short*)(ws + 46474240);        // 15,360,000  [8][NN][32]
    int*            cur  = (int*)(ws + 61834240);                   //    120,000
    unsigned short* col  = (unsigned short*)(ws + 61954240);        //  5,760,000  (~67.7 MB)

    ln_kernel<<<NN, 256, 0, stream>>>(s, gamma, beta, xh);
    wt_kernel<<<(768 * 256 + 255) / 256, 256, 0, stream>>>(Wqkv, WT);
    init_kernel<<<(NN * CAP / 2 + 255) / 256, 256, 0, stream>>>(
        cur, (unsigned int*)col, (unsigned int*)qs, (unsigned int*)vs);
    scatter_kernel<<<(NE + 255) / 256, 256, 0, stream>>>(src, dst, cur, col);
    gemm_kernel<<<1440, 256, 0, stream>>>(xh, WT, qs, ks, vs);
    edge_kernel<<<dim3(8, NN / 16), 256, 0, stream>>>(qs, vs, ks, cur, col, out);
}

// Round 11
// 215.951 us; speedup vs baseline: 1.6466x; 1.0014x over previous
//
#include <hip/hip_runtime.h>
#include <hip/hip_fp16.h>
#include <string.h>

#define NN 30000
#define NE 480000
#define CAP 96
#define KSC (0.0625f * 1.44269504f)   // SCALE * log2(e): exp(q*k/16) = exp2(q*kk)

typedef __attribute__((ext_vector_type(8))) _Float16 f16x8;
typedef __attribute__((ext_vector_type(4))) float f32x4;
typedef __attribute__((ext_vector_type(4))) int i32x4;

__device__ __forceinline__ unsigned short f2h(float f) {
    _Float16 h = (_Float16)f;
    unsigned short u;
    memcpy(&u, &h, 2);
    return u;
}

__device__ __forceinline__ void gload16(const void* g, void* l) {
    __builtin_amdgcn_global_load_lds(
        (const __attribute__((address_space(1))) unsigned int*)g,
        (__attribute__((address_space(3))) unsigned int*)l, 16, 0, 0);
}

// ---------------- LayerNorm -> fp16 x ----------------
__global__ __launch_bounds__(256) void ln_kernel(const float* __restrict__ s,
                                                 const float* __restrict__ gamma,
                                                 const float* __restrict__ beta,
                                                 unsigned short* __restrict__ xh) {
    const int n = blockIdx.x;
    const int c = threadIdx.x;
    float v = s[n * 256 + c];
    float sum = v, sq = v * v;
    for (int o = 32; o; o >>= 1) {
        sum += __shfl_down(sum, o, 64);
        sq  += __shfl_down(sq,  o, 64);
    }
    __shared__ float ssum[4], ssq[4];
    const int wave = c >> 6, lane = c & 63;
    if (lane == 0) { ssum[wave] = sum; ssq[wave] = sq; }
    __syncthreads();
    float ts = ssum[0] + ssum[1] + ssum[2] + ssum[3];
    float tq = ssq[0]  + ssq[1]  + ssq[2]  + ssq[3];
    float mu  = ts * (1.0f / 256.0f);
    float var = tq * (1.0f / 256.0f) - mu * mu;
    float x = (v - mu) * rsqrtf(var + 1e-5f) * gamma[c] + beta[c];
    xh[n * 256 + c] = f2h(x);
}

// ---------------- Wqkv [256,768] f32 -> WT [768,256] fp16 ----------------
__global__ __launch_bounds__(256) void wt_kernel(const float* __restrict__ W,
                                                 unsigned short* __restrict__ WT) {
    const int idx = blockIdx.x * 256 + threadIdx.x;
    if (idx < 768 * 256) {
        const int n = idx >> 8;
        const int k = idx & 255;
        WT[idx] = f2h(W[k * 768 + n]);
    }
}

// ---------------- init: zero cursor, sentinel-fill col, zero sentinel rows ----
__global__ __launch_bounds__(256) void init_kernel(int* __restrict__ cur,
                                                   unsigned int* __restrict__ colu,   // NN*CAP/2 uints
                                                   unsigned int* __restrict__ qs,
                                                   unsigned int* __restrict__ vs) {
    const int i = blockIdx.x * 256 + threadIdx.x;
    const unsigned int sent2 = (unsigned int)NN | ((unsigned int)NN << 16);
    if (i < NN * CAP / 2) colu[i] = sent2;
    if (i < NN) cur[i] = 0;
    if (i < 8 * 16) {  // 8 slices x 16 uints = sentinel row (32 ushorts) of qs/vs
        const int x = i >> 4, j = i & 15;
        qs[((size_t)x * (NN + 1) + NN) * 16 + j] = 0u;
        vs[((size_t)x * (NN + 1) + NN) * 16 + j] = 0u;
    }
}

__global__ __launch_bounds__(256) void scatter_kernel(const int* __restrict__ src,
                                                      const int* __restrict__ dst,
                                                      int* __restrict__ cursor,
                                                      unsigned short* __restrict__ col) {
    const int e = blockIdx.x * 256 + threadIdx.x;
    if (e < NE) {
        const int d = dst[e];
        const int slot = atomicAdd(&cursor[d], 1);
        if (slot < CAP) col[d * CAP + slot] = (unsigned short)src[e];
    }
}

// ---------------- GEMM: m97-style, XCD-banded, sliced epilogue ----------------
#define BM 128
#define BN 128
#define BK 32
#define CSTRIDE 136
#define MTILES 235   // ceil(30000/128)

__global__ __launch_bounds__(256) void gemm_kernel(const unsigned short* __restrict__ A,
                                                   const unsigned short* __restrict__ B,
                                                   unsigned short* __restrict__ qb,   // [8][NN+1][32]
                                                   unsigned short* __restrict__ kb,   // [8][NN][32]
                                                   unsigned short* __restrict__ vb) { // [8][NN+1][32]
    const int f   = blockIdx.x;          // 0..1439
    const int xcd = f & 7;
    const int i   = f >> 3;              // 0..179
    const int bmi = xcd * 30 + i / 6;
    if (bmi >= MTILES) return;
    const int bm = bmi * BM;
    const int by = i % 6;
    const int bn = by * BN;

    __shared__ unsigned short smem[BM * CSTRIDE];
    unsigned short* As = smem;
    unsigned short* Bs = smem + 4096;

    const int tid  = threadIdx.x;
    const int lane = tid & 63;
    const int wave = tid >> 6;
    const int wm = (wave & 1) * 64;
    const int wn = (wave >> 1) * 64;
    const int l16  = lane & 15;
    const int quad = lane >> 4;

    const int srow = wave * 16 + (lane >> 2);
    const int ko   = (lane & 3) * 8;

    int gmA0 = bm + srow;       if (gmA0 >= NN) gmA0 = NN - 1;
    int gmA1 = bm + srow + 64;  if (gmA1 >= NN) gmA1 = NN - 1;
    const int gnB0 = bn + srow;
    const int gnB1 = bn + srow + 64;

    f32x4 acc[4][4] = {};

    for (int kt = 0; kt < 256; kt += BK) {
        gload16(A + (size_t)gmA0 * 256 + kt + ko, &As[(wave * 16) * 32]);
        gload16(A + (size_t)gmA1 * 256 + kt + ko, &As[(64 + wave * 16) * 32]);
        gload16(B + (size_t)gnB0 * 256 + kt + ko, &Bs[(wave * 16) * 32]);
        gload16(B + (size_t)gnB1 * 256 + kt + ko, &Bs[(64 + wave * 16) * 32]);
        __syncthreads();

        f16x8 af[4], bfr[4];
        #pragma unroll
        for (int ii = 0; ii < 4; ii++)
            af[ii]  = *(const f16x8*)(&As[(wm + ii * 16 + l16) * 32 + quad * 8]);
        #pragma unroll
        for (int j = 0; j < 4; j++)
            bfr[j] = *(const f16x8*)(&Bs[(wn + j * 16 + l16) * 32 + quad * 8]);
        #pragma unroll
        for (int ii = 0; ii < 4; ii++)
            #pragma unroll
            for (int j = 0; j < 4; j++)
                acc[ii][j] = __builtin_amdgcn_mfma_f32_16x16x32_f16(af[ii], bfr[j], acc[ii][j], 0, 0, 0);
        __syncthreads();
    }

    #pragma unroll
    for (int ii = 0; ii < 4; ii++)
        #pragma unroll
        for (int j = 0; j < 4; j++)
            #pragma unroll
            for (int r = 0; r < 4; r++)
                smem[(wm + ii * 16 + quad * 4 + r) * CSTRIDE + wn + j * 16 + l16] =
                    f2h(acc[ii][j][r]);
    __syncthreads();

    const int sector  = by >> 1;                 // 0=q,1=k,2=v
    const int colhalf = (by & 1) * 128;
    const int row  = tid >> 1;
    const int cseg = (tid & 1) * 64;
    const int grow = bm + row;
    if (grow < NN) {
        #pragma unroll
        for (int k = 0; k < 8; k++) {
            i32x4 val = *(const i32x4*)(&smem[row * CSTRIDE + cseg + k * 8]);
            const int c = colhalf + cseg + k * 8;    // 8-aligned, 0..255
            const int x = c >> 5;                    // slice
            if (sector == 1)
                *(i32x4*)(kb + ((size_t)x * NN + grow) * 32 + (c & 31)) = val;
            else if (sector == 0)
                *(i32x4*)(qb + ((size_t)x * (NN + 1) + grow) * 32 + (c & 31)) = val;
            else
                *(i32x4*)(vb + ((size_t)x * (NN + 1) + grow) * 32 + (c & 31)) = val;
        }
    }
}

// ---------------- edge: in-block sort + sentinel + half2 + b128 index batch ----------------
__global__ __launch_bounds__(256) void edge_kernel(const unsigned short* __restrict__ qs,  // [8][NN+1][32]
                                                   const unsigned short* __restrict__ vs,  // [8][NN+1][32]
                                                   const unsigned short* __restrict__ ks,  // [8][NN][32]
                                                   const int* __restrict__ cursor,
                                                   const unsigned short* __restrict__ col, // [NN][CAP] sentinel-padded
                                                   float* __restrict__ out) {
    const int x    = blockIdx.x;            // slice 0..7 -> XCD (round-robin)
    const int nb   = blockIdx.y * 16;       // block's 16 nodes (sequential band)
    const int tid  = threadIdx.x;
    const int wave = tid >> 6;
    const int lane = tid & 63;

    __shared__ unsigned short scol[16 * CAP];   // 3072 B, rows 192 B (16B-aligned)
    __shared__ int sdegR[16];
    __shared__ int sdegS[16];
    __shared__ int snode[16];

    if (tid < 16) {
        int d = cursor[nb + tid];
        sdegR[tid] = (d > CAP) ? CAP : d;
    }
    __syncthreads();
    if (tid < 16) {
        const int d = sdegR[tid];
        int r = 0;
        #pragma unroll
        for (int j = 0; j < 16; ++j) {
            const int dj = sdegR[j];
            r += (dj < d) || (dj == d && j < tid);
        }
        sdegS[r] = d;
        snode[r] = nb + tid;
    }
    __syncthreads();
    {   // stage col rows in sorted order
        const unsigned int* colu = (const unsigned int*)col;
        unsigned int* scolu = (unsigned int*)scol;
        #pragma unroll
        for (int j = 0; j < 3; j++) {
            const int t2 = tid + j * 256;            // 0..767
            const int nd = t2 / 48;                  // local rank
            const int ps = t2 - nd * 48;
            scolu[t2] = colu[snode[nd] * 48 + ps];
        }
    }
    __syncthreads();

    const int g     = lane >> 4;            // node-in-wave 0..3
    const int cpair = lane & 15;            // channel pair
    const int li    = wave * 4 + g;
    const int m     = snode[li];            // true node id

    const int mydeg = sdegS[li];
    const int dmax8 = (sdegS[wave * 4 + 3] + 7) & ~7;   // sorted: quartet max at rank 3; <=96

    union H2 { unsigned int u; __half2 h; };
    H2 kw;
    kw.u = *(const unsigned int*)(ks + ((size_t)x * NN + m) * 32 + 2 * cpair);
    const __half2 kk2 = __hmul2(kw.h, __float2half2_rn(KSC));

    const unsigned short* qp = qs + (size_t)x * (NN + 1) * 32 + 2 * cpair;
    const unsigned short* vp = vs + (size_t)x * (NN + 1) * 32 + 2 * cpair;
    const unsigned short* myscol = &scol[li * CAP];

    __half2 zA = __float2half2_rn(0.0f), zB = __float2half2_rn(0.0f);
    __half2 aA = __float2half2_rn(0.0f), aB = __float2half2_rn(0.0f);

    for (int i = 0; i < dmax8; i += 8) {
        const i32x4 idx4 = *(const i32x4*)(&myscol[i]);   // 8 indices, one ds_read_b128
        H2 qd[8], vd[8];
        #pragma unroll
        for (int j = 0; j < 8; j++) {
            const int s = (idx4[j >> 1] >> ((j & 1) * 16)) & 0xffff;  // sentinel NN when padded
            qd[j].u = *(const unsigned int*)(qp + (size_t)s * 32);
            vd[j].u = *(const unsigned int*)(vp + (size_t)s * 32);
        }
        #pragma unroll
        for (int j = 0; j < 8; j += 2) {
            const __half2 w0 = h2exp2(__hmul2(qd[j].h, kk2));       // sentinel: exp2(0)=1
            const __half2 w1 = h2exp2(__hmul2(qd[j + 1].h, kk2));
            zA = __hadd2(zA, w0);
            aA = __hfma2(w0, vd[j].h, aA);
            zB = __hadd2(zB, w1);
            aB = __hfma2(w1, vd[j + 1].h, aB);
        }
    }

    const __half2 z2 = __hadd2(zA, zB);
    const __half2 a2 = __hadd2(aA, aB);

    // sentinel pads contributed exactly 1.0 to z, 0.0 to a — exact correction:
    const float npad = (float)(dmax8 - mydeg);
    const float z0 = __low2float(z2)  - npad;
    const float z1 = __high2float(z2) - npad;
    const float a0 = __low2float(a2);
    const float a1 = __high2float(a2);

    float2 o;
    o.x = (mydeg > 0) ? a0 / z0 : 0.0f;
    o.y = (mydeg > 0) ? a1 / z1 : 0.0f;
    *(float2*)(out + (size_t)m * 256 + x * 32 + 2 * cpair) = o;
}

extern "C" void kernel_launch(void* const* d_in, const int* in_sizes, int n_in,
                              void* d_out, int out_size, void* d_ws, size_t ws_size,
                              hipStream_t stream) {
    const float* s     = (const float*)d_in[0];
    const float* Wqkv  = (const float*)d_in[1];
    const float* gamma = (const float*)d_in[2];
    const float* beta  = (const float*)d_in[3];
    const int*   src   = (const int*)d_in[4];
    const int*   dst   = (const int*)d_in[5];
    float* out = (float*)d_out;

    char* ws = (char*)d_ws;
    unsigned short* xh   = (unsigned short*)(ws);                   // 15,360,000
    unsigned short* WT   = (unsigned short*)(ws + 15360000);        //    393,216
    unsigned short* qs   = (unsigned short*)(ws + 15753216);        // 15,360,512  [8][NN+1][32]
    unsigned short* vs   = (unsigned short*)(ws + 31113728);        // 15,360,512
    unsigned short* ks   = (unsigned short*)(ws + 46474240);        // 15,360,000  [8][NN][32]
    int*            cur  = (int*)(ws + 61834240);                   //    120,000
    unsigned short* col  = (unsigned short*)(ws + 61954240);        //  5,760,000  (~67.7 MB)

    ln_kernel<<<NN, 256, 0, stream>>>(s, gamma, beta, xh);
    wt_kernel<<<(768 * 256 + 255) / 256, 256, 0, stream>>>(Wqkv, WT);
    init_kernel<<<(NN * CAP / 2 + 255) / 256, 256, 0, stream>>>(
        cur, (unsigned int*)col, (unsigned int*)qs, (unsigned int*)vs);
    scatter_kernel<<<(NE + 255) / 256, 256, 0, stream>>>(src, dst, cur, col);
    gemm_kernel<<<1440, 256, 0, stream>>>(xh, WT, qs, ks, vs);
    edge_kernel<<<dim3(8, NN / 16), 256, 0, stream>>>(qs, vs, ks, cur, col, out);
}